// Round 1
// baseline (977.887 us; speedup 1.0000x reference)
//
#include <hip/hip_runtime.h>

typedef __attribute__((ext_vector_type(4))) float  f32x4;
typedef __attribute__((ext_vector_type(8))) short  s16x8;
typedef __attribute__((ext_vector_type(4))) float  f4v;

#define MFMA_BF16 __builtin_amdgcn_mfma_f32_16x16x32_bf16

// ---------- helpers ----------
__device__ __forceinline__ short f2bf(float f) {
  unsigned u = __builtin_bit_cast(unsigned, f);
  u += 0x7fffu + ((u >> 16) & 1u);          // round-to-nearest-even
  return (short)(u >> 16);
}

__device__ __forceinline__ s16x8 cvt8(f4v f0, f4v f1) {
  s16x8 r;
  r[0] = f2bf(f0[0]); r[1] = f2bf(f0[1]); r[2] = f2bf(f0[2]); r[3] = f2bf(f0[3]);
  r[4] = f2bf(f1[0]); r[5] = f2bf(f1[1]); r[6] = f2bf(f1[2]); r[7] = f2bf(f1[3]);
  return r;
}

// ---------- weight prep: fragment-ready bf16 layout ----------
// W1p: 9 ksteps x 8 ntiles x 1KB chunks (K padded 272->288), at wp[0]
// W2p: 4 ksteps x 8 ntiles x 1KB chunks,                    at wp[36864] (shorts)
__global__ __launch_bounds__(256) void prep_weights(
    const float* __restrict__ W1, const float* __restrict__ W2,
    short* __restrict__ wp) {
  int t = blockIdx.x * 256 + threadIdx.x;
  int chunk = t >> 6, l = t & 63;
  if (chunk >= 104) return;
  int q = l >> 4, c = l & 15;
  s16x8 v;
  if (chunk < 72) {
    int kk = chunk >> 3, nt = chunk & 7;
    int k0 = kk * 32 + q * 8, n = nt * 16 + c;
#pragma unroll
    for (int j = 0; j < 8; ++j) {
      int k = k0 + j;
      v[j] = (k < 272) ? f2bf(W1[k * 128 + n]) : (short)0;
    }
    *reinterpret_cast<s16x8*>(wp + (size_t)chunk * 512 + l * 8) = v;
  } else {
    int c2 = chunk - 72;
    int kk = c2 >> 3, nt = c2 & 7;
    int k0 = kk * 32 + q * 8, n = nt * 16 + c;
#pragma unroll
    for (int j = 0; j < 8; ++j) v[j] = f2bf(W2[(k0 + j) * 128 + n]);
    *reinterpret_cast<s16x8*>(wp + 36864 + (size_t)c2 * 512 + l * 8) = v;
  }
}

// ---------- fused edge MLP + scatter ----------
// block: 256 thr = 4 waves; each wave owns 64 edges (4 M-fragments of 16).
// GEMM1: [64 x 288] x [288 x 128], A gathered global->reg (bf16 cvt in flight)
// epilogue1: +b1, SiLU -> wave-private LDS tile (bf16, stride 136)
// GEMM2: [64 x 128] x [128 x 128] via ds_read_b128 A-frags
// epilogue2: +b2, unsafeAtomicAdd scatter to out[row]
__global__ __launch_bounds__(256, 2) void edge_mlp(
    const float* __restrict__ h, const int* __restrict__ ei,
    const float* __restrict__ bond, const short* __restrict__ wp,
    const float* __restrict__ b1, const float* __restrict__ b2,
    float* __restrict__ out, int E) {
  __shared__ __align__(16) short Plds[4][64][136];
  __shared__ int rows_s[256];
  __shared__ int cols_s[256];

  const int tid = threadIdx.x;
  const int w = tid >> 6, l = tid & 63;
  const int q = l >> 4, c = l & 15;
  const int eb = blockIdx.x * 256;

  { // stage edge indices (clamped for tail)
    int e = eb + tid; if (e >= E) e = E - 1;
    rows_s[tid] = ei[e];
    cols_s[tid] = ei[(size_t)E + e];
  }
  __syncthreads();

  const int we = w * 64;  // wave's base edge within block
  int rN[4], cN[4], eI[4];
#pragma unroll
  for (int mi = 0; mi < 4; ++mi) {
    int el = we + mi * 16 + c;
    rN[mi] = rows_s[el];
    cN[mi] = cols_s[el];
    int eg = eb + el; if (eg >= E) eg = E - 1;
    eI[mi] = eg;
  }

  f32x4 acc[4][8];
#pragma unroll
  for (int mi = 0; mi < 4; ++mi)
#pragma unroll
    for (int nt = 0; nt < 8; ++nt) acc[mi][nt] = (f32x4){0.f, 0.f, 0.f, 0.f};

  // ---- GEMM1 phase 1+2: h[row] (k 0..127), h[col] (k 128..255) ----
#pragma unroll
  for (int part = 0; part < 2; ++part) {
#pragma unroll
    for (int kk = 0; kk < 4; ++kk) {
      s16x8 a[4];
#pragma unroll
      for (int mi = 0; mi < 4; ++mi) {
        int node = part ? cN[mi] : rN[mi];
        const float* src = h + (size_t)node * 128 + kk * 32 + q * 8;
        f4v f0 = *reinterpret_cast<const f4v*>(src);
        f4v f1 = *reinterpret_cast<const f4v*>(src + 4);
        a[mi] = cvt8(f0, f1);
      }
      const int kkg = part * 4 + kk;
#pragma unroll
      for (int nt = 0; nt < 8; ++nt) {
        s16x8 b = *reinterpret_cast<const s16x8*>(wp + (size_t)(kkg * 8 + nt) * 512 + l * 8);
#pragma unroll
        for (int mi = 0; mi < 4; ++mi)
          acc[mi][nt] = MFMA_BF16(a[mi], b, acc[mi][nt], 0, 0, 0);
      }
    }
  }
  // ---- GEMM1 phase 3: bond (k 256..271) + zero pad (272..287) ----
  {
    s16x8 a[4];
#pragma unroll
    for (int mi = 0; mi < 4; ++mi) {
      s16x8 az = {};
      if (q < 2) {
        const float* src = bond + (size_t)eI[mi] * 16 + q * 8;
        f4v f0 = *reinterpret_cast<const f4v*>(src);
        f4v f1 = *reinterpret_cast<const f4v*>(src + 4);
        az = cvt8(f0, f1);
      }
      a[mi] = az;
    }
#pragma unroll
    for (int nt = 0; nt < 8; ++nt) {
      s16x8 b = *reinterpret_cast<const s16x8*>(wp + (size_t)(8 * 8 + nt) * 512 + l * 8);
#pragma unroll
      for (int mi = 0; mi < 4; ++mi)
        acc[mi][nt] = MFMA_BF16(a[mi], b, acc[mi][nt], 0, 0, 0);
    }
  }

  // ---- epilogue 1: bias + SiLU -> LDS (wave-private slice, no barrier) ----
#pragma unroll
  for (int nt = 0; nt < 8; ++nt) {
    float bias = b1[nt * 16 + c];
#pragma unroll
    for (int mi = 0; mi < 4; ++mi)
#pragma unroll
      for (int r = 0; r < 4; ++r) {
        float x = acc[mi][nt][r] + bias;
        float s = x / (1.f + __expf(-x));
        Plds[w][mi * 16 + q * 4 + r][nt * 16 + c] = f2bf(s);
      }
  }

  // ---- GEMM2: P[64x128] @ W2[128x128] ----
  f32x4 acc2[4][8];
#pragma unroll
  for (int mi = 0; mi < 4; ++mi)
#pragma unroll
    for (int nt = 0; nt < 8; ++nt) acc2[mi][nt] = (f32x4){0.f, 0.f, 0.f, 0.f};

#pragma unroll
  for (int kk = 0; kk < 4; ++kk) {
    s16x8 a2[4];
#pragma unroll
    for (int mi = 0; mi < 4; ++mi)
      a2[mi] = *reinterpret_cast<const s16x8*>(&Plds[w][mi * 16 + c][kk * 32 + q * 8]);
#pragma unroll
    for (int nt = 0; nt < 8; ++nt) {
      s16x8 b = *reinterpret_cast<const s16x8*>(wp + 36864 + (size_t)(kk * 8 + nt) * 512 + l * 8);
#pragma unroll
      for (int mi = 0; mi < 4; ++mi)
        acc2[mi][nt] = MFMA_BF16(a2[mi], b, acc2[mi][nt], 0, 0, 0);
    }
  }

  // ---- epilogue 2: bias + atomic scatter to out[row] ----
#pragma unroll
  for (int nt = 0; nt < 8; ++nt) {
    float bias = b2[nt * 16 + c];
#pragma unroll
    for (int mi = 0; mi < 4; ++mi)
#pragma unroll
      for (int r = 0; r < 4; ++r) {
        int el = we + mi * 16 + q * 4 + r;
        bool valid = (eb + el) < E;
        if (valid) {
          int node = rows_s[el];
          unsafeAtomicAdd(&out[(size_t)node * 128 + nt * 16 + c],
                          acc2[mi][nt][r] + bias);
        }
      }
  }
}

extern "C" void kernel_launch(void* const* d_in, const int* in_sizes, int n_in,
                              void* d_out, int out_size, void* d_ws, size_t ws_size,
                              hipStream_t stream) {
  const float* h    = (const float*)d_in[0];
  const int*   ei   = (const int*)d_in[1];
  const float* bond = (const float*)d_in[2];
  const float* W1   = (const float*)d_in[3];
  const float* b1   = (const float*)d_in[4];
  const float* W2   = (const float*)d_in[5];
  const float* b2   = (const float*)d_in[6];
  float* out = (float*)d_out;
  short* wp  = (short*)d_ws;   // needs 106,496 B

  const int E  = in_sizes[1] / 2;
  const int NN = in_sizes[0] / 128;

  hipMemsetAsync(d_out, 0, (size_t)NN * 128 * sizeof(float), stream);
  prep_weights<<<26, 256, 0, stream>>>(W1, W2, wp);
  const int nblk = (E + 255) / 256;
  edge_mlp<<<nblk, 256, 0, stream>>>(h, ei, bond, wp, b1, b2, out, E);
}

// Round 2
// 783.078 us; speedup vs baseline: 1.2488x; 1.2488x over previous
//
#include <hip/hip_runtime.h>

typedef __attribute__((ext_vector_type(4))) float  f32x4;
typedef __attribute__((ext_vector_type(8))) short  s16x8;
typedef __attribute__((ext_vector_type(4))) float  f4v;

#define MFMA_BF16 __builtin_amdgcn_mfma_f32_16x16x32_bf16

// ---------- helpers ----------
__device__ __forceinline__ short f2bf(float f) {
  unsigned u = __builtin_bit_cast(unsigned, f);
  u += 0x7fffu + ((u >> 16) & 1u);          // round-to-nearest-even
  return (short)(u >> 16);
}
__device__ __forceinline__ float bf2f(short s) {
  unsigned u = ((unsigned)(unsigned short)s) << 16;
  return __builtin_bit_cast(float, u);
}
__device__ __forceinline__ s16x8 cvt8(f4v f0, f4v f1) {
  s16x8 r;
  r[0] = f2bf(f0[0]); r[1] = f2bf(f0[1]); r[2] = f2bf(f0[2]); r[3] = f2bf(f0[3]);
  r[4] = f2bf(f1[0]); r[5] = f2bf(f1[1]); r[6] = f2bf(f1[2]); r[7] = f2bf(f1[3]);
  return r;
}

// ---------- weight prep: fragment-ready bf16 layout (verified round 1) ----------
// W1p: 9 ksteps x 8 ntiles x 1KB chunks (K padded 272->288), at wp[0]
// W2p: 4 ksteps x 8 ntiles x 1KB chunks,                     at wp[36864] (shorts)
__global__ __launch_bounds__(256) void prep_weights(
    const float* __restrict__ W1, const float* __restrict__ W2,
    short* __restrict__ wp) {
  int t = blockIdx.x * 256 + threadIdx.x;
  int chunk = t >> 6, l = t & 63;
  if (chunk >= 104) return;
  int q = l >> 4, c = l & 15;
  s16x8 v;
  if (chunk < 72) {
    int kk = chunk >> 3, nt = chunk & 7;
    int k0 = kk * 32 + q * 8, n = nt * 16 + c;
#pragma unroll
    for (int j = 0; j < 8; ++j) {
      int k = k0 + j;
      v[j] = (k < 272) ? f2bf(W1[k * 128 + n]) : (short)0;
    }
    *reinterpret_cast<s16x8*>(wp + (size_t)chunk * 512 + l * 8) = v;
  } else {
    int c2 = chunk - 72;
    int kk = c2 >> 3, nt = c2 & 7;
    int k0 = kk * 32 + q * 8, n = nt * 16 + c;
#pragma unroll
    for (int j = 0; j < 8; ++j) v[j] = f2bf(W2[(k0 + j) * 128 + n]);
    *reinterpret_cast<s16x8*>(wp + 36864 + (size_t)c2 * 512 + l * 8) = v;
  }
}

// ---------- dense precompute: G[NN][256] (bf16) = h @ [W1a | W1b] ----------
// G[n][0:128]   = (h @ W1[0:128,:])[n]      (row term)
// G[n][128:256] = (h @ W1[128:256,:])[n]    (col term)
// 4 waves/block, each wave: 16 nodes x 256 cols. acc = 16 x f32x4.
__global__ __launch_bounds__(256) void dense_g(
    const float* __restrict__ h, const short* __restrict__ wp,
    short* __restrict__ G, int NN) {
  const int tid = threadIdx.x;
  const int w = tid >> 6, l = tid & 63;
  const int q = l >> 4, c = l & 15;
  const int nb = blockIdx.x * 64 + w * 16;

  f32x4 acc[16];
#pragma unroll
  for (int nt = 0; nt < 16; ++nt) acc[nt] = (f32x4){0.f, 0.f, 0.f, 0.f};

#pragma unroll
  for (int kk = 0; kk < 4; ++kk) {
    int node = nb + c; if (node >= NN) node = NN - 1;
    const float* src = h + (size_t)node * 128 + kk * 32 + q * 8;
    f4v f0 = *reinterpret_cast<const f4v*>(src);
    f4v f1 = *reinterpret_cast<const f4v*>(src + 4);
    s16x8 a = cvt8(f0, f1);
#pragma unroll
    for (int nt2 = 0; nt2 < 16; ++nt2) {
      int kkg = kk + ((nt2 >= 8) ? 4 : 0);     // W1a rows 0..127, W1b rows 128..255
      int chunk = kkg * 8 + (nt2 & 7);
      s16x8 b = *reinterpret_cast<const s16x8*>(wp + (size_t)chunk * 512 + l * 8);
      acc[nt2] = MFMA_BF16(a, b, acc[nt2], 0, 0, 0);
    }
  }
#pragma unroll
  for (int nt2 = 0; nt2 < 16; ++nt2)
#pragma unroll
    for (int r = 0; r < 4; ++r) {
      int node = nb + q * 4 + r;
      if (node < NN) G[(size_t)node * 256 + nt2 * 16 + c] = f2bf(acc[nt2][r]);
    }
}

// ---------- fused edge kernel v2 ----------
// block: 256 thr = 4 waves; each wave owns 32 edges (2 M-fragments).
// 1) bond @ W1c via MFMA (K=16 pad 32)  -> C-layout acc
// 2) (+b1) -> LDS (bf16, stride 136)     [layout bridge C->A]
// 3) GEMM2 A-frags built in registers: silu(G1[row]+G2[col]+bond+b1)
// 4) GEMM2 MFMA, +b2, unsafeAtomicAdd scatter
__global__ __launch_bounds__(256, 3) void edge_mlp2(
    const short* __restrict__ G, const int* __restrict__ ei,
    const float* __restrict__ bond, const short* __restrict__ wp,
    const float* __restrict__ b1, const float* __restrict__ b2,
    float* __restrict__ out, int E) {
  __shared__ __align__(16) short Plds[4][32][136];
  __shared__ int rows_s[128];
  __shared__ int cols_s[128];

  const int tid = threadIdx.x;
  const int w = tid >> 6, l = tid & 63;
  const int q = l >> 4, c = l & 15;
  const int eb = blockIdx.x * 128;

  if (tid < 128) {
    int e = eb + tid; if (e >= E) e = E - 1;
    rows_s[tid] = ei[e];
    cols_s[tid] = ei[(size_t)E + e];
  }
  __syncthreads();

  const int we = w * 32;
  // per-lane edge ids in the A domain (edge = we + mi*16 + c)
  int rA[2], cA[2], eA[2];
#pragma unroll
  for (int mi = 0; mi < 2; ++mi) {
    int el = we + mi * 16 + c;
    rA[mi] = rows_s[el];
    cA[mi] = cols_s[el];
    int eg = eb + el; if (eg >= E) eg = E - 1;
    eA[mi] = eg;
  }

  // ---- bond @ W1c ----
  f32x4 accb[2][8];
#pragma unroll
  for (int mi = 0; mi < 2; ++mi)
#pragma unroll
    for (int nt = 0; nt < 8; ++nt) accb[mi][nt] = (f32x4){0.f, 0.f, 0.f, 0.f};

  {
    s16x8 a[2];
#pragma unroll
    for (int mi = 0; mi < 2; ++mi) {
      s16x8 az = {};
      if (q < 2) {
        const float* src = bond + (size_t)eA[mi] * 16 + q * 8;
        f4v f0 = *reinterpret_cast<const f4v*>(src);
        f4v f1 = *reinterpret_cast<const f4v*>(src + 4);
        az = cvt8(f0, f1);
      }
      a[mi] = az;
    }
#pragma unroll
    for (int nt = 0; nt < 8; ++nt) {
      s16x8 b = *reinterpret_cast<const s16x8*>(wp + (size_t)(64 + nt) * 512 + l * 8);
#pragma unroll
      for (int mi = 0; mi < 2; ++mi)
        accb[mi][nt] = MFMA_BF16(a[mi], b, accb[mi][nt], 0, 0, 0);
    }
  }

  // ---- bridge C->A layout through LDS, fold b1 ----
#pragma unroll
  for (int nt = 0; nt < 8; ++nt) {
    float bias = b1[nt * 16 + c];
#pragma unroll
    for (int mi = 0; mi < 2; ++mi)
#pragma unroll
      for (int r = 0; r < 4; ++r)
        Plds[w][mi * 16 + q * 4 + r][nt * 16 + c] = f2bf(accb[mi][nt][r] + bias);
  }
  // wave-private LDS RAW: compiler-inserted lgkmcnt waits suffice (no barrier)

  // ---- GEMM2 with A built from gathered G + bond term ----
  f32x4 acc2[2][8];
#pragma unroll
  for (int mi = 0; mi < 2; ++mi)
#pragma unroll
    for (int nt = 0; nt < 8; ++nt) acc2[mi][nt] = (f32x4){0.f, 0.f, 0.f, 0.f};

#pragma unroll
  for (int kk = 0; kk < 4; ++kk) {
    s16x8 a2[2];
#pragma unroll
    for (int mi = 0; mi < 2; ++mi) {
      s16x8 g1 = *reinterpret_cast<const s16x8*>(G + (size_t)rA[mi] * 256 + kk * 32 + q * 8);
      s16x8 g2 = *reinterpret_cast<const s16x8*>(G + (size_t)cA[mi] * 256 + 128 + kk * 32 + q * 8);
      s16x8 pb = *reinterpret_cast<const s16x8*>(&Plds[w][mi * 16 + c][kk * 32 + q * 8]);
      s16x8 r;
#pragma unroll
      for (int j = 0; j < 8; ++j) {
        float x = bf2f(g1[j]) + bf2f(g2[j]) + bf2f(pb[j]);
        float e = __expf(-x);
        float s = x * __builtin_amdgcn_rcpf(1.f + e);
        r[j] = f2bf(s);
      }
      a2[mi] = r;
    }
#pragma unroll
    for (int nt = 0; nt < 8; ++nt) {
      s16x8 b = *reinterpret_cast<const s16x8*>(wp + 36864 + (size_t)(kk * 8 + nt) * 512 + l * 8);
#pragma unroll
      for (int mi = 0; mi < 2; ++mi)
        acc2[mi][nt] = MFMA_BF16(a2[mi], b, acc2[mi][nt], 0, 0, 0);
    }
  }

  // ---- +b2, atomic scatter ----
#pragma unroll
  for (int nt = 0; nt < 8; ++nt) {
    float bias = b2[nt * 16 + c];
#pragma unroll
    for (int mi = 0; mi < 2; ++mi)
#pragma unroll
      for (int r = 0; r < 4; ++r) {
        int el = we + mi * 16 + q * 4 + r;
        if ((eb + el) < E) {
          int node = rows_s[el];
          unsafeAtomicAdd(&out[(size_t)node * 128 + nt * 16 + c],
                          acc2[mi][nt][r] + bias);
        }
      }
  }
}

// ---------- fallback edge kernel (round-1, verified) for small ws ----------
__global__ __launch_bounds__(256, 2) void edge_mlp(
    const float* __restrict__ h, const int* __restrict__ ei,
    const float* __restrict__ bond, const short* __restrict__ wp,
    const float* __restrict__ b1, const float* __restrict__ b2,
    float* __restrict__ out, int E) {
  __shared__ __align__(16) short Plds[4][64][136];
  __shared__ int rows_s[256];
  __shared__ int cols_s[256];
  const int tid = threadIdx.x;
  const int w = tid >> 6, l = tid & 63;
  const int q = l >> 4, c = l & 15;
  const int eb = blockIdx.x * 256;
  {
    int e = eb + tid; if (e >= E) e = E - 1;
    rows_s[tid] = ei[e];
    cols_s[tid] = ei[(size_t)E + e];
  }
  __syncthreads();
  const int we = w * 64;
  int rN[4], cN[4], eI[4];
#pragma unroll
  for (int mi = 0; mi < 4; ++mi) {
    int el = we + mi * 16 + c;
    rN[mi] = rows_s[el]; cN[mi] = cols_s[el];
    int eg = eb + el; if (eg >= E) eg = E - 1;
    eI[mi] = eg;
  }
  f32x4 acc[4][8];
#pragma unroll
  for (int mi = 0; mi < 4; ++mi)
#pragma unroll
    for (int nt = 0; nt < 8; ++nt) acc[mi][nt] = (f32x4){0.f, 0.f, 0.f, 0.f};
#pragma unroll
  for (int part = 0; part < 2; ++part) {
#pragma unroll
    for (int kk = 0; kk < 4; ++kk) {
      s16x8 a[4];
#pragma unroll
      for (int mi = 0; mi < 4; ++mi) {
        int node = part ? cN[mi] : rN[mi];
        const float* src = h + (size_t)node * 128 + kk * 32 + q * 8;
        a[mi] = cvt8(*reinterpret_cast<const f4v*>(src),
                     *reinterpret_cast<const f4v*>(src + 4));
      }
      const int kkg = part * 4 + kk;
#pragma unroll
      for (int nt = 0; nt < 8; ++nt) {
        s16x8 b = *reinterpret_cast<const s16x8*>(wp + (size_t)(kkg * 8 + nt) * 512 + l * 8);
#pragma unroll
        for (int mi = 0; mi < 4; ++mi)
          acc[mi][nt] = MFMA_BF16(a[mi], b, acc[mi][nt], 0, 0, 0);
      }
    }
  }
  {
    s16x8 a[4];
#pragma unroll
    for (int mi = 0; mi < 4; ++mi) {
      s16x8 az = {};
      if (q < 2) {
        const float* src = bond + (size_t)eI[mi] * 16 + q * 8;
        az = cvt8(*reinterpret_cast<const f4v*>(src),
                  *reinterpret_cast<const f4v*>(src + 4));
      }
      a[mi] = az;
    }
#pragma unroll
    for (int nt = 0; nt < 8; ++nt) {
      s16x8 b = *reinterpret_cast<const s16x8*>(wp + (size_t)(64 + nt) * 512 + l * 8);
#pragma unroll
      for (int mi = 0; mi < 4; ++mi)
        acc[mi][nt] = MFMA_BF16(a[mi], b, acc[mi][nt], 0, 0, 0);
    }
  }
#pragma unroll
  for (int nt = 0; nt < 8; ++nt) {
    float bias = b1[nt * 16 + c];
#pragma unroll
    for (int mi = 0; mi < 4; ++mi)
#pragma unroll
      for (int r = 0; r < 4; ++r) {
        float x = acc[mi][nt][r] + bias;
        float s = x / (1.f + __expf(-x));
        Plds[w][mi * 16 + q * 4 + r][nt * 16 + c] = f2bf(s);
      }
  }
  f32x4 acc2[4][8];
#pragma unroll
  for (int mi = 0; mi < 4; ++mi)
#pragma unroll
    for (int nt = 0; nt < 8; ++nt) acc2[mi][nt] = (f32x4){0.f, 0.f, 0.f, 0.f};
#pragma unroll
  for (int kk = 0; kk < 4; ++kk) {
    s16x8 a2[4];
#pragma unroll
    for (int mi = 0; mi < 4; ++mi)
      a2[mi] = *reinterpret_cast<const s16x8*>(&Plds[w][mi * 16 + c][kk * 32 + q * 8]);
#pragma unroll
    for (int nt = 0; nt < 8; ++nt) {
      s16x8 b = *reinterpret_cast<const s16x8*>(wp + 36864 + (size_t)(kk * 8 + nt) * 512 + l * 8);
#pragma unroll
      for (int mi = 0; mi < 4; ++mi)
        acc2[mi][nt] = MFMA_BF16(a2[mi], b, acc2[mi][nt], 0, 0, 0);
    }
  }
#pragma unroll
  for (int nt = 0; nt < 8; ++nt) {
    float bias = b2[nt * 16 + c];
#pragma unroll
    for (int mi = 0; mi < 4; ++mi)
#pragma unroll
      for (int r = 0; r < 4; ++r) {
        int el = we + mi * 16 + q * 4 + r;
        if ((eb + el) < E) {
          int node = rows_s[el];
          unsafeAtomicAdd(&out[(size_t)node * 128 + nt * 16 + c],
                          acc2[mi][nt][r] + bias);
        }
      }
  }
}

extern "C" void kernel_launch(void* const* d_in, const int* in_sizes, int n_in,
                              void* d_out, int out_size, void* d_ws, size_t ws_size,
                              hipStream_t stream) {
  const float* h    = (const float*)d_in[0];
  const int*   ei   = (const int*)d_in[1];
  const float* bond = (const float*)d_in[2];
  const float* W1   = (const float*)d_in[3];
  const float* b1   = (const float*)d_in[4];
  const float* W2   = (const float*)d_in[5];
  const float* b2   = (const float*)d_in[6];
  float* out = (float*)d_out;
  short* wp  = (short*)d_ws;                    // 106,496 B of weight fragments

  const int E  = in_sizes[1] / 2;
  const int NN = in_sizes[0] / 128;

  const size_t G_OFF_SHORTS = 65536;            // 128 KiB byte offset
  short* G = wp + G_OFF_SHORTS;
  const size_t need = 131072 + (size_t)NN * 256 * 2;

  hipMemsetAsync(d_out, 0, (size_t)NN * 128 * sizeof(float), stream);
  prep_weights<<<26, 256, 0, stream>>>(W1, W2, wp);

  if (ws_size >= need) {
    dense_g<<<(NN + 63) / 64, 256, 0, stream>>>(h, wp, G, NN);
    edge_mlp2<<<(E + 127) / 128, 256, 0, stream>>>(G, ei, bond, wp, b1, b2, out, E);
  } else {
    edge_mlp<<<(E + 255) / 256, 256, 0, stream>>>(h, ei, bond, wp, b1, b2, out, E);
  }
}

// Round 3
// 540.386 us; speedup vs baseline: 1.8096x; 1.4491x over previous
//
#include <hip/hip_runtime.h>

typedef __attribute__((ext_vector_type(4))) float  f32x4;
typedef __attribute__((ext_vector_type(8))) short  s16x8;
typedef __attribute__((ext_vector_type(4))) float  f4v;

#define MFMA_BF16 __builtin_amdgcn_mfma_f32_16x16x32_bf16
#define SENT 0x7fffffff

// ---------- helpers ----------
__device__ __forceinline__ short f2bf(float f) {
  unsigned u = __builtin_bit_cast(unsigned, f);
  u += 0x7fffu + ((u >> 16) & 1u);          // round-to-nearest-even
  return (short)(u >> 16);
}
__device__ __forceinline__ float bf2f(short s) {
  unsigned u = ((unsigned)(unsigned short)s) << 16;
  return __builtin_bit_cast(float, u);
}
__device__ __forceinline__ s16x8 cvt8(f4v f0, f4v f1) {
  s16x8 r;
  r[0] = f2bf(f0[0]); r[1] = f2bf(f0[1]); r[2] = f2bf(f0[2]); r[3] = f2bf(f0[3]);
  r[4] = f2bf(f1[0]); r[5] = f2bf(f1[1]); r[6] = f2bf(f1[2]); r[7] = f2bf(f1[3]);
  return r;
}

// ---------- weight prep (verified r1/r2) ----------
__global__ __launch_bounds__(256) void prep_weights(
    const float* __restrict__ W1, const float* __restrict__ W2,
    short* __restrict__ wp) {
  int t = blockIdx.x * 256 + threadIdx.x;
  int chunk = t >> 6, l = t & 63;
  if (chunk >= 104) return;
  int q = l >> 4, c = l & 15;
  s16x8 v;
  if (chunk < 72) {
    int kk = chunk >> 3, nt = chunk & 7;
    int k0 = kk * 32 + q * 8, n = nt * 16 + c;
#pragma unroll
    for (int j = 0; j < 8; ++j) {
      int k = k0 + j;
      v[j] = (k < 272) ? f2bf(W1[k * 128 + n]) : (short)0;
    }
    *reinterpret_cast<s16x8*>(wp + (size_t)chunk * 512 + l * 8) = v;
  } else {
    int c2 = chunk - 72;
    int kk = c2 >> 3, nt = c2 & 7;
    int k0 = kk * 32 + q * 8, n = nt * 16 + c;
#pragma unroll
    for (int j = 0; j < 8; ++j) v[j] = f2bf(W2[(k0 + j) * 128 + n]);
    *reinterpret_cast<s16x8*>(wp + 36864 + (size_t)c2 * 512 + l * 8) = v;
  }
}

// ---------- dense precompute: G[NN][256] bf16 = h @ [W1a | W1b] (verified r2) ----------
__global__ __launch_bounds__(256) void dense_g(
    const float* __restrict__ h, const short* __restrict__ wp,
    short* __restrict__ G, int NN) {
  const int tid = threadIdx.x;
  const int w = tid >> 6, l = tid & 63;
  const int q = l >> 4, c = l & 15;
  const int nb = blockIdx.x * 64 + w * 16;

  f32x4 acc[16];
#pragma unroll
  for (int nt = 0; nt < 16; ++nt) acc[nt] = (f32x4){0.f, 0.f, 0.f, 0.f};

#pragma unroll
  for (int kk = 0; kk < 4; ++kk) {
    int node = nb + c; if (node >= NN) node = NN - 1;
    const float* src = h + (size_t)node * 128 + kk * 32 + q * 8;
    s16x8 a = cvt8(*reinterpret_cast<const f4v*>(src),
                   *reinterpret_cast<const f4v*>(src + 4));
#pragma unroll
    for (int nt2 = 0; nt2 < 16; ++nt2) {
      int kkg = kk + ((nt2 >= 8) ? 4 : 0);
      int chunk = kkg * 8 + (nt2 & 7);
      s16x8 b = *reinterpret_cast<const s16x8*>(wp + (size_t)chunk * 512 + l * 8);
      acc[nt2] = MFMA_BF16(a, b, acc[nt2], 0, 0, 0);
    }
  }
#pragma unroll
  for (int nt2 = 0; nt2 < 16; ++nt2)
#pragma unroll
    for (int r = 0; r < 4; ++r) {
      int node = nb + q * 4 + r;
      if (node < NN) G[(size_t)node * 256 + nt2 * 16 + c] = f2bf(acc[nt2][r]);
    }
}

// ---------- sort-by-row machinery ----------
__global__ void k_hist(const int* __restrict__ ei, int* __restrict__ cnt, int E) {
  int i = blockIdx.x * blockDim.x + threadIdx.x;
  int stride = gridDim.x * blockDim.x;
  for (; i < E; i += stride) atomicAdd(&cnt[ei[i]], 1);
}

__global__ __launch_bounds__(1024) void k_scan(int* __restrict__ cnt, int NN) {
  __shared__ int ps[1024];
  int t = threadIdx.x;
  int chunk = (NN + 1023) / 1024;
  int lo = t * chunk, hi = min(lo + chunk, NN);
  int s = 0;
  for (int i = lo; i < hi; ++i) s += cnt[i];
  ps[t] = s; __syncthreads();
  for (int d = 1; d < 1024; d <<= 1) {
    int v = (t >= d) ? ps[t - d] : 0;
    __syncthreads();
    ps[t] += v;
    __syncthreads();
  }
  int base = ps[t] - s;                 // exclusive prefix
  for (int i = lo; i < hi; ++i) { int c = cnt[i]; cnt[i] = base; base += c; }
}

__global__ void k_scatter(const int* __restrict__ ei, const int* __restrict__ offs,
                          int* __restrict__ tmp, int* __restrict__ perm, int E) {
  int i = blockIdx.x * blockDim.x + threadIdx.x;
  int stride = gridDim.x * blockDim.x;
  for (; i < E; i += stride) {
    int r = ei[i];
    int pos = offs[r] + atomicAdd(&tmp[r], 1);
    perm[pos] = i;
  }
}

// ---------- fused edge kernel v3 (sorted edges, LDS segment-reduce) ----------
// 4 waves x 32 sorted edges. Epilogue: per-wave 32x128 tile -> LDS (fp32, 2 halves
// of 64 cols, unioned with dead Plds), column-walk with per-segment atomic flush.
__global__ __launch_bounds__(256, 4) void edge_mlp3(
    const short* __restrict__ G, const int* __restrict__ ei,
    const int* __restrict__ perm,
    const float* __restrict__ bond, const short* __restrict__ wp,
    const float* __restrict__ b1, const float* __restrict__ b2,
    float* __restrict__ out, int E) {
  __shared__ __align__(16) char ubuf[4 * 32 * 136 * 2];   // 34816 B, Plds/Sred union
  short (*Plds)[32][136] = reinterpret_cast<short(*)[32][136]>(ubuf);
  float (*Sred)[32][68]  = reinterpret_cast<float(*)[32][68]>(ubuf);
  __shared__ int rows_s[128];
  __shared__ int cols_s[128];
  __shared__ int eidx_s[128];

  const int tid = threadIdx.x;
  const int w = tid >> 6, l = tid & 63;
  const int q = l >> 4, c = l & 15;
  const int eb = blockIdx.x * 128;

  if (tid < 128) {
    int gpos = eb + tid;
    int e = (gpos < E) ? perm[gpos] : -1;
    eidx_s[tid] = (e < 0) ? 0 : e;
    rows_s[tid] = (e < 0) ? SENT : ei[e];
    cols_s[tid] = (e < 0) ? 0 : ei[(size_t)E + e];
  }
  __syncthreads();

  const int we = w * 32;
  int rA[2], cA[2], eA[2];
#pragma unroll
  for (int mi = 0; mi < 2; ++mi) {
    int el = we + mi * 16 + c;
    int rr = rows_s[el];
    rA[mi] = (rr == SENT) ? 0 : rr;
    cA[mi] = cols_s[el];
    eA[mi] = eidx_s[el];
  }

  // ---- bond @ W1c ----
  f32x4 accb[2][8];
#pragma unroll
  for (int mi = 0; mi < 2; ++mi)
#pragma unroll
    for (int nt = 0; nt < 8; ++nt) accb[mi][nt] = (f32x4){0.f, 0.f, 0.f, 0.f};
  {
    s16x8 a[2];
#pragma unroll
    for (int mi = 0; mi < 2; ++mi) {
      s16x8 az = {};
      if (q < 2) {
        const float* src = bond + (size_t)eA[mi] * 16 + q * 8;
        az = cvt8(*reinterpret_cast<const f4v*>(src),
                  *reinterpret_cast<const f4v*>(src + 4));
      }
      a[mi] = az;
    }
#pragma unroll
    for (int nt = 0; nt < 8; ++nt) {
      s16x8 b = *reinterpret_cast<const s16x8*>(wp + (size_t)(64 + nt) * 512 + l * 8);
#pragma unroll
      for (int mi = 0; mi < 2; ++mi)
        accb[mi][nt] = MFMA_BF16(a[mi], b, accb[mi][nt], 0, 0, 0);
    }
  }

  // ---- bridge C->A through LDS, fold b1 (wave-private) ----
#pragma unroll
  for (int nt = 0; nt < 8; ++nt) {
    float bias = b1[nt * 16 + c];
#pragma unroll
    for (int mi = 0; mi < 2; ++mi)
#pragma unroll
      for (int r = 0; r < 4; ++r)
        Plds[w][mi * 16 + q * 4 + r][nt * 16 + c] = f2bf(accb[mi][nt][r] + bias);
  }

  // ---- GEMM2: A = silu(G1[row] + G2[col] + bondterm) ----
  f32x4 acc2[2][8];
#pragma unroll
  for (int mi = 0; mi < 2; ++mi)
#pragma unroll
    for (int nt = 0; nt < 8; ++nt) acc2[mi][nt] = (f32x4){0.f, 0.f, 0.f, 0.f};

#pragma unroll
  for (int kk = 0; kk < 4; ++kk) {
    s16x8 a2[2];
#pragma unroll
    for (int mi = 0; mi < 2; ++mi) {
      s16x8 g1 = *reinterpret_cast<const s16x8*>(G + (size_t)rA[mi] * 256 + kk * 32 + q * 8);
      s16x8 g2 = *reinterpret_cast<const s16x8*>(G + (size_t)cA[mi] * 256 + 128 + kk * 32 + q * 8);
      s16x8 pb = *reinterpret_cast<const s16x8*>(&Plds[w][mi * 16 + c][kk * 32 + q * 8]);
      s16x8 r;
#pragma unroll
      for (int j = 0; j < 8; ++j) {
        float x = bf2f(g1[j]) + bf2f(g2[j]) + bf2f(pb[j]);
        float e = __expf(-x);
        float s = x * __builtin_amdgcn_rcpf(1.f + e);
        r[j] = f2bf(s);
      }
      a2[mi] = r;
    }
#pragma unroll
    for (int nt = 0; nt < 8; ++nt) {
      s16x8 b = *reinterpret_cast<const s16x8*>(wp + 36864 + (size_t)(kk * 8 + nt) * 512 + l * 8);
#pragma unroll
      for (int mi = 0; mi < 2; ++mi)
        acc2[mi][nt] = MFMA_BF16(a2[mi], b, acc2[mi][nt], 0, 0, 0);
    }
  }

  // ---- epilogue: two 64-col halves, LDS tile + sorted column-walk ----
#pragma unroll
  for (int h2 = 0; h2 < 2; ++h2) {
    __syncthreads();   // previous union/walk readers done before overwrite
#pragma unroll
    for (int nt2 = 0; nt2 < 4; ++nt2) {
      int nt = h2 * 4 + nt2;
      float bias = b2[nt * 16 + c];
#pragma unroll
      for (int mi = 0; mi < 2; ++mi)
#pragma unroll
        for (int r = 0; r < 4; ++r)
          Sred[w][mi * 16 + q * 4 + r][nt2 * 16 + c] = acc2[mi][nt][r] + bias;
    }
    __syncthreads();
    // column-walk: lane owns column h2*64 + l of this wave's 32 sorted rows
    float vsum = 0.f;
    int cur = rows_s[we];
#pragma unroll 8
    for (int r = 0; r < 32; ++r) {
      vsum += Sred[w][r][l];
      int nxt = (r < 31) ? rows_s[we + r + 1] : -1;
      if (nxt != cur) {
        if (cur != SENT)
          unsafeAtomicAdd(&out[(size_t)cur * 128 + h2 * 64 + l], vsum);
        vsum = 0.f;
        cur = nxt;
      }
    }
  }
}

// ---------- fallback (round-2 verified) ----------
__global__ __launch_bounds__(256, 3) void edge_mlp2(
    const short* __restrict__ G, const int* __restrict__ ei,
    const float* __restrict__ bond, const short* __restrict__ wp,
    const float* __restrict__ b1, const float* __restrict__ b2,
    float* __restrict__ out, int E) {
  __shared__ __align__(16) short Plds[4][32][136];
  __shared__ int rows_s[128];
  __shared__ int cols_s[128];
  const int tid = threadIdx.x;
  const int w = tid >> 6, l = tid & 63;
  const int q = l >> 4, c = l & 15;
  const int eb = blockIdx.x * 128;
  if (tid < 128) {
    int e = eb + tid; if (e >= E) e = E - 1;
    rows_s[tid] = ei[e];
    cols_s[tid] = ei[(size_t)E + e];
  }
  __syncthreads();
  const int we = w * 32;
  int rA[2], cA[2], eA[2];
#pragma unroll
  for (int mi = 0; mi < 2; ++mi) {
    int el = we + mi * 16 + c;
    rA[mi] = rows_s[el]; cA[mi] = cols_s[el];
    int eg = eb + el; if (eg >= E) eg = E - 1;
    eA[mi] = eg;
  }
  f32x4 accb[2][8];
#pragma unroll
  for (int mi = 0; mi < 2; ++mi)
#pragma unroll
    for (int nt = 0; nt < 8; ++nt) accb[mi][nt] = (f32x4){0.f, 0.f, 0.f, 0.f};
  {
    s16x8 a[2];
#pragma unroll
    for (int mi = 0; mi < 2; ++mi) {
      s16x8 az = {};
      if (q < 2) {
        const float* src = bond + (size_t)eA[mi] * 16 + q * 8;
        az = cvt8(*reinterpret_cast<const f4v*>(src),
                  *reinterpret_cast<const f4v*>(src + 4));
      }
      a[mi] = az;
    }
#pragma unroll
    for (int nt = 0; nt < 8; ++nt) {
      s16x8 b = *reinterpret_cast<const s16x8*>(wp + (size_t)(64 + nt) * 512 + l * 8);
#pragma unroll
      for (int mi = 0; mi < 2; ++mi)
        accb[mi][nt] = MFMA_BF16(a[mi], b, accb[mi][nt], 0, 0, 0);
    }
  }
#pragma unroll
  for (int nt = 0; nt < 8; ++nt) {
    float bias = b1[nt * 16 + c];
#pragma unroll
    for (int mi = 0; mi < 2; ++mi)
#pragma unroll
      for (int r = 0; r < 4; ++r)
        Plds[w][mi * 16 + q * 4 + r][nt * 16 + c] = f2bf(accb[mi][nt][r] + bias);
  }
  f32x4 acc2[2][8];
#pragma unroll
  for (int mi = 0; mi < 2; ++mi)
#pragma unroll
    for (int nt = 0; nt < 8; ++nt) acc2[mi][nt] = (f32x4){0.f, 0.f, 0.f, 0.f};
#pragma unroll
  for (int kk = 0; kk < 4; ++kk) {
    s16x8 a2[2];
#pragma unroll
    for (int mi = 0; mi < 2; ++mi) {
      s16x8 g1 = *reinterpret_cast<const s16x8*>(G + (size_t)rA[mi] * 256 + kk * 32 + q * 8);
      s16x8 g2 = *reinterpret_cast<const s16x8*>(G + (size_t)cA[mi] * 256 + 128 + kk * 32 + q * 8);
      s16x8 pb = *reinterpret_cast<const s16x8*>(&Plds[w][mi * 16 + c][kk * 32 + q * 8]);
      s16x8 r;
#pragma unroll
      for (int j = 0; j < 8; ++j) {
        float x = bf2f(g1[j]) + bf2f(g2[j]) + bf2f(pb[j]);
        float e = __expf(-x);
        float s = x * __builtin_amdgcn_rcpf(1.f + e);
        r[j] = f2bf(s);
      }
      a2[mi] = r;
    }
#pragma unroll
    for (int nt = 0; nt < 8; ++nt) {
      s16x8 b = *reinterpret_cast<const s16x8*>(wp + 36864 + (size_t)(kk * 8 + nt) * 512 + l * 8);
#pragma unroll
      for (int mi = 0; mi < 2; ++mi)
        acc2[mi][nt] = MFMA_BF16(a2[mi], b, acc2[mi][nt], 0, 0, 0);
    }
  }
#pragma unroll
  for (int nt = 0; nt < 8; ++nt) {
    float bias = b2[nt * 16 + c];
#pragma unroll
    for (int mi = 0; mi < 2; ++mi)
#pragma unroll
      for (int r = 0; r < 4; ++r) {
        int el = we + mi * 16 + q * 4 + r;
        if ((eb + el) < E) {
          int node = rows_s[el];
          unsafeAtomicAdd(&out[(size_t)node * 128 + nt * 16 + c],
                          acc2[mi][nt][r] + bias);
        }
      }
  }
}

extern "C" void kernel_launch(void* const* d_in, const int* in_sizes, int n_in,
                              void* d_out, int out_size, void* d_ws, size_t ws_size,
                              hipStream_t stream) {
  const float* h    = (const float*)d_in[0];
  const int*   ei   = (const int*)d_in[1];
  const float* bond = (const float*)d_in[2];
  const float* W1   = (const float*)d_in[3];
  const float* b1   = (const float*)d_in[4];
  const float* W2   = (const float*)d_in[5];
  const float* b2   = (const float*)d_in[6];
  float* out = (float*)d_out;
  char* ws = (char*)d_ws;

  const int E  = in_sizes[1] / 2;
  const int NN = in_sizes[0] / 128;

  // workspace layout (bytes)
  short* wp = (short*)ws;                                   // 131072
  size_t off_G    = 131072;
  size_t off_cnt  = off_G + (size_t)NN * 256 * 2;           // G: 25.6 MB
  size_t off_tmp  = off_cnt + (size_t)NN * 4;
  size_t off_perm = off_tmp + (size_t)NN * 4;
  size_t need_full = off_perm + (size_t)E * 4;
  size_t need_v2   = off_cnt;

  short* G   = (short*)(ws + off_G);
  int* cnt   = (int*)(ws + off_cnt);
  int* tmp   = (int*)(ws + off_tmp);
  int* perm  = (int*)(ws + off_perm);

  hipMemsetAsync(d_out, 0, (size_t)NN * 128 * sizeof(float), stream);
  prep_weights<<<26, 256, 0, stream>>>(W1, W2, wp);

  if (ws_size >= need_full) {
    hipMemsetAsync(cnt, 0, (size_t)NN * 8, stream);         // cnt + tmp
    dense_g<<<(NN + 63) / 64, 256, 0, stream>>>(h, wp, G, NN);
    k_hist<<<2048, 256, 0, stream>>>(ei, cnt, E);
    k_scan<<<1, 1024, 0, stream>>>(cnt, NN);
    k_scatter<<<2048, 256, 0, stream>>>(ei, cnt, tmp, perm, E);
    edge_mlp3<<<(E + 127) / 128, 256, 0, stream>>>(G, ei, perm, bond, wp, b1, b2, out, E);
  } else if (ws_size >= need_v2) {
    dense_g<<<(NN + 63) / 64, 256, 0, stream>>>(h, wp, G, NN);
    edge_mlp2<<<(E + 127) / 128, 256, 0, stream>>>(G, ei, bond, wp, b1, b2, out, E);
  }
}

// Round 4
// 497.685 us; speedup vs baseline: 1.9649x; 1.0858x over previous
//
#include <hip/hip_runtime.h>

typedef __attribute__((ext_vector_type(4))) float  f32x4;
typedef __attribute__((ext_vector_type(8))) short  s16x8;
typedef __attribute__((ext_vector_type(4))) float  f4v;
typedef __attribute__((ext_vector_type(4))) int    i32x4;

#define MFMA_BF16 __builtin_amdgcn_mfma_f32_16x16x32_bf16
#define SENT 0x7fffffff

// ---------- helpers ----------
__device__ __forceinline__ short f2bf(float f) {
  unsigned u = __builtin_bit_cast(unsigned, f);
  u += 0x7fffu + ((u >> 16) & 1u);
  return (short)(u >> 16);
}
__device__ __forceinline__ float bf2f(short s) {
  unsigned u = ((unsigned)(unsigned short)s) << 16;
  return __builtin_bit_cast(float, u);
}
__device__ __forceinline__ s16x8 cvt8(f4v f0, f4v f1) {
  s16x8 r;
  r[0] = f2bf(f0[0]); r[1] = f2bf(f0[1]); r[2] = f2bf(f0[2]); r[3] = f2bf(f0[3]);
  r[4] = f2bf(f1[0]); r[5] = f2bf(f1[1]); r[6] = f2bf(f1[2]); r[7] = f2bf(f1[3]);
  return r;
}
// fp8 e4m3fn encode (RTNE, |x|<2^-6 -> 0, clamp 448)
__device__ __forceinline__ unsigned f2fp8(float x) {
  unsigned u = __builtin_bit_cast(unsigned, x);
  unsigned s = (u >> 24) & 0x80u;
  unsigned au = u & 0x7fffffffu;
  if (au < 0x3C800000u) return s;              // below min-normal -> signed zero
  unsigned biased = au - 0x3C000000u;          // rebias 127 -> 7
  unsigned val = biased >> 20;
  unsigned rem = biased & 0xFFFFFu;
  val += (rem > 0x80000u) || (rem == 0x80000u && (val & 1u));
  if (val > 0x7Eu) val = 0x7Eu;
  return s | val;
}
// fp8 e4m3fn decode (denormals -> 0)
__device__ __forceinline__ float fp8tof(unsigned b) {
  unsigned em = b & 0x7fu;
  unsigned f = ((em + 960u) << 20) | ((b & 0x80u) << 24);
  return (em < 8u) ? 0.f : __builtin_bit_cast(float, f);
}

// ---------- weight prep (verified r1-r3) ----------
// W1p: 9 ksteps x 8 ntiles x 1KB chunks (K padded 272->288) at wp[0]
// W2p: 4 ksteps x 8 ntiles at wp[36864] (shorts)
__global__ __launch_bounds__(256) void prep_weights(
    const float* __restrict__ W1, const float* __restrict__ W2,
    short* __restrict__ wp) {
  int t = blockIdx.x * 256 + threadIdx.x;
  int chunk = t >> 6, l = t & 63;
  if (chunk >= 104) return;
  int q = l >> 4, c = l & 15;
  s16x8 v;
  if (chunk < 72) {
    int kk = chunk >> 3, nt = chunk & 7;
    int k0 = kk * 32 + q * 8, n = nt * 16 + c;
#pragma unroll
    for (int j = 0; j < 8; ++j) {
      int k = k0 + j;
      v[j] = (k < 272) ? f2bf(W1[k * 128 + n]) : (short)0;
    }
    *reinterpret_cast<s16x8*>(wp + (size_t)chunk * 512 + l * 8) = v;
  } else {
    int c2 = chunk - 72;
    int kk = c2 >> 3, nt = c2 & 7;
    int k0 = kk * 32 + q * 8, n = nt * 16 + c;
#pragma unroll
    for (int j = 0; j < 8; ++j) v[j] = f2bf(W2[(k0 + j) * 128 + n]);
    *reinterpret_cast<s16x8*>(wp + 36864 + (size_t)c2 * 512 + l * 8) = v;
  }
}

// ---------- fused dense G + edge histogram ----------
// G layout per node: 384 B = [128 bf16 G1 (row half)] [128 B fp8 G2 (col half, permuted)]
// G2 byte addr for col: q2=(col&31)>>3, kk2=col>>5, j=col&7 -> q2*32 + kk2*8 + j
#define NB_H 512
__global__ __launch_bounds__(256) void k_gh(
    const float* __restrict__ h, const short* __restrict__ wp,
    short* __restrict__ Gs, const int* __restrict__ ei,
    int* __restrict__ cnt, int NN, int NB_G, int E) {
  if ((int)blockIdx.x >= NB_G) {
    int i = ((int)blockIdx.x - NB_G) * 256 + threadIdx.x;
    for (; i < E; i += NB_H * 256) atomicAdd(&cnt[ei[i]], 1);
    return;
  }
  const int tid = threadIdx.x;
  const int w = tid >> 6, l = tid & 63;
  const int q = l >> 4, c = l & 15;
  const int nb = blockIdx.x * 64 + w * 16;

  f32x4 acc[16];
#pragma unroll
  for (int nt = 0; nt < 16; ++nt) acc[nt] = (f32x4){0.f, 0.f, 0.f, 0.f};

#pragma unroll
  for (int kk = 0; kk < 4; ++kk) {
    int node = nb + c; if (node >= NN) node = NN - 1;
    const float* src = h + (size_t)node * 128 + kk * 32 + q * 8;
    s16x8 a = cvt8(*reinterpret_cast<const f4v*>(src),
                   *reinterpret_cast<const f4v*>(src + 4));
#pragma unroll
    for (int nt2 = 0; nt2 < 16; ++nt2) {
      int kkg = kk + ((nt2 >= 8) ? 4 : 0);
      int chunk = kkg * 8 + (nt2 & 7);
      s16x8 b = *reinterpret_cast<const s16x8*>(wp + (size_t)chunk * 512 + l * 8);
      acc[nt2] = MFMA_BF16(a, b, acc[nt2], 0, 0, 0);
    }
  }
  unsigned char* Gb = (unsigned char*)Gs;
#pragma unroll
  for (int nt2 = 0; nt2 < 16; ++nt2)
#pragma unroll
    for (int r = 0; r < 4; ++r) {
      int node = nb + q * 4 + r;
      if (node < NN) {
        if (nt2 < 8) {
          Gs[(size_t)node * 192 + nt2 * 16 + c] = f2bf(acc[nt2][r]);
        } else {
          int n7 = nt2 - 8;
          int addr = ((n7 & 1) * 2 + (c >> 3)) * 32 + (n7 >> 1) * 8 + (c & 7);
          Gb[(size_t)node * 384 + 256 + addr] = (unsigned char)f2fp8(acc[nt2][r]);
        }
      }
    }
}

// ---------- 3-phase exclusive scan over cnt[NN] ----------
__global__ __launch_bounds__(1024) void k_s1(const int* __restrict__ cnt,
                                             int* __restrict__ partial, int NN) {
  __shared__ int red[16];
  int t = threadIdx.x, idx = blockIdx.x * 1024 + t;
  int v = (idx < NN) ? cnt[idx] : 0;
#pragma unroll
  for (int d = 1; d < 64; d <<= 1) v += __shfl_xor(v, d);
  if ((t & 63) == 0) red[t >> 6] = v;
  __syncthreads();
  if (t == 0) {
    int s = 0;
#pragma unroll
    for (int i = 0; i < 16; ++i) s += red[i];
    partial[blockIdx.x] = s;
  }
}
__global__ __launch_bounds__(1024) void k_s2(int* __restrict__ partial, int P) {
  __shared__ int ps[1024];
  int t = threadIdx.x;
  int v = (t < P) ? partial[t] : 0;
  ps[t] = v; __syncthreads();
  for (int d = 1; d < 1024; d <<= 1) {
    int u = (t >= d) ? ps[t - d] : 0;
    __syncthreads(); ps[t] += u; __syncthreads();
  }
  if (t < P) partial[t] = ps[t] - v;
}
__global__ __launch_bounds__(1024) void k_s3(int* __restrict__ cnt,
                                             const int* __restrict__ partial, int NN) {
  __shared__ int ps[1024];
  int t = threadIdx.x, idx = blockIdx.x * 1024 + t;
  int v = (idx < NN) ? cnt[idx] : 0;
  ps[t] = v; __syncthreads();
  for (int d = 1; d < 1024; d <<= 1) {
    int u = (t >= d) ? ps[t - d] : 0;
    __syncthreads(); ps[t] += u; __syncthreads();
  }
  if (idx < NN) cnt[idx] = ps[t] - v + partial[blockIdx.x];
}

// ---------- scatter: build sorted packed (row|col<<16, eidx) ----------
__global__ void k_scatter(const int* __restrict__ ei, int* __restrict__ cnt,
                          int2* __restrict__ rce, int E) {
  int i = blockIdx.x * blockDim.x + threadIdx.x;
  int stride = gridDim.x * blockDim.x;
  for (; i < E; i += stride) {
    int r = ei[i], c = ei[(size_t)E + i];
    int pos = atomicAdd(&cnt[r], 1);
    rce[pos] = make_int2(r | (c << 16), i);
  }
}

// ---------- fused edge kernel v4 ----------
// 4 waves x 32 sorted edges; hoisted g1(bf16)/g2(fp8) gathers; bond MFMA bridge;
// silu in A-domain; GEMM2; LDS segment-reduce scatter (round-3 verified epilogue).
__global__ __launch_bounds__(256, 3) void edge_mlp4(
    const short* __restrict__ Gs, const int2* __restrict__ rce,
    const float* __restrict__ bond, const short* __restrict__ wp,
    const float* __restrict__ b1, const float* __restrict__ b2,
    float* __restrict__ out, int E) {
  __shared__ __align__(16) char ubuf[4 * 32 * 136 * 2];   // Plds/Sred union
  short (*Plds)[32][136] = reinterpret_cast<short(*)[32][136]>(ubuf);
  float (*Sred)[32][68]  = reinterpret_cast<float(*)[32][68]>(ubuf);
  __shared__ int rows_s[128];
  __shared__ int cols_s[128];
  __shared__ int eidx_s[128];

  const int tid = threadIdx.x;
  const int w = tid >> 6, l = tid & 63;
  const int q = l >> 4, c = l & 15;

  // XCD-chunked bijective swizzle (consecutive sorted blocks -> same XCD)
  int nwg = gridDim.x;
  int qq = nwg >> 3, rr = nwg & 7;
  int xcd = blockIdx.x & 7, idx = blockIdx.x >> 3;
  int sbid = (xcd < rr ? xcd * (qq + 1) : rr * (qq + 1) + (xcd - rr) * qq) + idx;
  const int eb = sbid * 128;

  if (tid < 128) {
    int gpos = eb + tid;
    if (gpos < E) {
      int2 v = rce[gpos];
      rows_s[tid] = v.x & 0xffff;
      cols_s[tid] = ((unsigned)v.x) >> 16;
      eidx_s[tid] = v.y;
    } else {
      rows_s[tid] = SENT; cols_s[tid] = 0; eidx_s[tid] = 0;
    }
  }
  __syncthreads();

  const int we = w * 32;
  int rA[2], cA[2], eA[2];
#pragma unroll
  for (int mi = 0; mi < 2; ++mi) {
    int el = we + mi * 16 + c;
    int rv = rows_s[el];
    rA[mi] = (rv == SENT) ? 0 : rv;
    cA[mi] = cols_s[el];
    eA[mi] = eidx_s[el];
  }

  // ---- hoisted gathers: g1 (bf16 row-half), g2 (fp8 col-half, permuted) ----
  s16x8 g1v[2][4];
  i32x4 g2v[2][2];
#pragma unroll
  for (int mi = 0; mi < 2; ++mi) {
    const short* gb = Gs + (size_t)rA[mi] * 192;
#pragma unroll
    for (int kk = 0; kk < 4; ++kk)
      g1v[mi][kk] = *reinterpret_cast<const s16x8*>(gb + kk * 32 + q * 8);
    const char* g2b = (const char*)Gs + (size_t)cA[mi] * 384 + 256 + q * 32;
    g2v[mi][0] = *reinterpret_cast<const i32x4*>(g2b);
    g2v[mi][1] = *reinterpret_cast<const i32x4*>(g2b + 16);
  }

  // ---- bond @ W1c (MFMA) ----
  f32x4 accb[2][8];
#pragma unroll
  for (int mi = 0; mi < 2; ++mi)
#pragma unroll
    for (int nt = 0; nt < 8; ++nt) accb[mi][nt] = (f32x4){0.f, 0.f, 0.f, 0.f};
  {
    s16x8 a[2];
#pragma unroll
    for (int mi = 0; mi < 2; ++mi) {
      s16x8 az = {};
      if (q < 2) {
        const float* src = bond + (size_t)eA[mi] * 16 + q * 8;
        az = cvt8(*reinterpret_cast<const f4v*>(src),
                  *reinterpret_cast<const f4v*>(src + 4));
      }
      a[mi] = az;
    }
#pragma unroll
    for (int nt = 0; nt < 8; ++nt) {
      s16x8 b = *reinterpret_cast<const s16x8*>(wp + (size_t)(64 + nt) * 512 + l * 8);
#pragma unroll
      for (int mi = 0; mi < 2; ++mi)
        accb[mi][nt] = MFMA_BF16(a[mi], b, accb[mi][nt], 0, 0, 0);
    }
  }

  // ---- bridge C->A through LDS, fold b1 (wave-private, no barrier) ----
#pragma unroll
  for (int nt = 0; nt < 8; ++nt) {
    float bias = b1[nt * 16 + c];
#pragma unroll
    for (int mi = 0; mi < 2; ++mi)
#pragma unroll
      for (int r = 0; r < 4; ++r)
        Plds[w][mi * 16 + q * 4 + r][nt * 16 + c] = f2bf(accb[mi][nt][r] + bias);
  }

  // ---- GEMM2: A = silu(g1 + g2 + bondterm) ----
  f32x4 acc2[2][8];
#pragma unroll
  for (int mi = 0; mi < 2; ++mi)
#pragma unroll
    for (int nt = 0; nt < 8; ++nt) acc2[mi][nt] = (f32x4){0.f, 0.f, 0.f, 0.f};

#pragma unroll
  for (int kk = 0; kk < 4; ++kk) {
    s16x8 a2[2];
#pragma unroll
    for (int mi = 0; mi < 2; ++mi) {
      s16x8 gk = g1v[mi][kk];
      unsigned d0 = (unsigned)g2v[mi][kk >> 1][(kk & 1) * 2 + 0];
      unsigned d1 = (unsigned)g2v[mi][kk >> 1][(kk & 1) * 2 + 1];
      s16x8 pb = *reinterpret_cast<const s16x8*>(&Plds[w][mi * 16 + c][kk * 32 + q * 8]);
      s16x8 r;
#pragma unroll
      for (int j = 0; j < 8; ++j) {
        unsigned byte = ((j < 4 ? d0 : d1) >> (8 * (j & 3))) & 0xffu;
        float x = bf2f(gk[j]) + fp8tof(byte) + bf2f(pb[j]);
        float e = __expf(-x);
        float s = x * __builtin_amdgcn_rcpf(1.f + e);
        r[j] = f2bf(s);
      }
      a2[mi] = r;
    }
#pragma unroll
    for (int nt = 0; nt < 8; ++nt) {
      s16x8 b = *reinterpret_cast<const s16x8*>(wp + 36864 + (size_t)(kk * 8 + nt) * 512 + l * 8);
#pragma unroll
      for (int mi = 0; mi < 2; ++mi)
        acc2[mi][nt] = MFMA_BF16(a2[mi], b, acc2[mi][nt], 0, 0, 0);
    }
  }

  // ---- epilogue: two 64-col halves, LDS tile + sorted column-walk ----
#pragma unroll
  for (int h2 = 0; h2 < 2; ++h2) {
    __syncthreads();
#pragma unroll
    for (int nt2 = 0; nt2 < 4; ++nt2) {
      int nt = h2 * 4 + nt2;
      float bias = b2[nt * 16 + c];
#pragma unroll
      for (int mi = 0; mi < 2; ++mi)
#pragma unroll
        for (int r = 0; r < 4; ++r)
          Sred[w][mi * 16 + q * 4 + r][nt2 * 16 + c] = acc2[mi][nt][r] + bias;
    }
    __syncthreads();
    float vsum = 0.f;
    int cur = rows_s[we];
#pragma unroll 8
    for (int r = 0; r < 32; ++r) {
      vsum += Sred[w][r][l];
      int nxt = (r < 31) ? rows_s[we + r + 1] : -1;
      if (nxt != cur) {
        if (cur != SENT)
          unsafeAtomicAdd(&out[(size_t)cur * 128 + h2 * 64 + l], vsum);
        vsum = 0.f;
        cur = nxt;
      }
    }
  }
}

// ---------- ultimate fallback (round-1 verified, wp-only) ----------
__global__ __launch_bounds__(256, 2) void edge_mlp(
    const float* __restrict__ h, const int* __restrict__ ei,
    const float* __restrict__ bond, const short* __restrict__ wp,
    const float* __restrict__ b1, const float* __restrict__ b2,
    float* __restrict__ out, int E) {
  __shared__ __align__(16) short Plds[4][64][136];
  __shared__ int rows_s[256];
  __shared__ int cols_s[256];
  const int tid = threadIdx.x;
  const int w = tid >> 6, l = tid & 63;
  const int q = l >> 4, c = l & 15;
  const int eb = blockIdx.x * 256;
  {
    int e = eb + tid; if (e >= E) e = E - 1;
    rows_s[tid] = ei[e];
    cols_s[tid] = ei[(size_t)E + e];
  }
  __syncthreads();
  const int we = w * 64;
  int rN[4], cN[4], eI[4];
#pragma unroll
  for (int mi = 0; mi < 4; ++mi) {
    int el = we + mi * 16 + c;
    rN[mi] = rows_s[el]; cN[mi] = cols_s[el];
    int eg = eb + el; if (eg >= E) eg = E - 1;
    eI[mi] = eg;
  }
  f32x4 acc[4][8];
#pragma unroll
  for (int mi = 0; mi < 4; ++mi)
#pragma unroll
    for (int nt = 0; nt < 8; ++nt) acc[mi][nt] = (f32x4){0.f, 0.f, 0.f, 0.f};
#pragma unroll
  for (int part = 0; part < 2; ++part) {
#pragma unroll
    for (int kk = 0; kk < 4; ++kk) {
      s16x8 a[4];
#pragma unroll
      for (int mi = 0; mi < 4; ++mi) {
        int node = part ? cN[mi] : rN[mi];
        const float* src = h + (size_t)node * 128 + kk * 32 + q * 8;
        a[mi] = cvt8(*reinterpret_cast<const f4v*>(src),
                     *reinterpret_cast<const f4v*>(src + 4));
      }
      const int kkg = part * 4 + kk;
#pragma unroll
      for (int nt = 0; nt < 8; ++nt) {
        s16x8 b = *reinterpret_cast<const s16x8*>(wp + (size_t)(kkg * 8 + nt) * 512 + l * 8);
#pragma unroll
        for (int mi = 0; mi < 4; ++mi)
          acc[mi][nt] = MFMA_BF16(a[mi], b, acc[mi][nt], 0, 0, 0);
      }
    }
  }
  {
    s16x8 a[4];
#pragma unroll
    for (int mi = 0; mi < 4; ++mi) {
      s16x8 az = {};
      if (q < 2) {
        const float* src = bond + (size_t)eI[mi] * 16 + q * 8;
        az = cvt8(*reinterpret_cast<const f4v*>(src),
                  *reinterpret_cast<const f4v*>(src + 4));
      }
      a[mi] = az;
    }
#pragma unroll
    for (int nt = 0; nt < 8; ++nt) {
      s16x8 b = *reinterpret_cast<const s16x8*>(wp + (size_t)(64 + nt) * 512 + l * 8);
#pragma unroll
      for (int mi = 0; mi < 4; ++mi)
        acc[mi][nt] = MFMA_BF16(a[mi], b, acc[mi][nt], 0, 0, 0);
    }
  }
#pragma unroll
  for (int nt = 0; nt < 8; ++nt) {
    float bias = b1[nt * 16 + c];
#pragma unroll
    for (int mi = 0; mi < 4; ++mi)
#pragma unroll
      for (int r = 0; r < 4; ++r) {
        float x = acc[mi][nt][r] + bias;
        float s = x / (1.f + __expf(-x));
        Plds[w][mi * 16 + q * 4 + r][nt * 16 + c] = f2bf(s);
      }
  }
  f32x4 acc2[4][8];
#pragma unroll
  for (int mi = 0; mi < 4; ++mi)
#pragma unroll
    for (int nt = 0; nt < 8; ++nt) acc2[mi][nt] = (f32x4){0.f, 0.f, 0.f, 0.f};
#pragma unroll
  for (int kk = 0; kk < 4; ++kk) {
    s16x8 a2[4];
#pragma unroll
    for (int mi = 0; mi < 4; ++mi)
      a2[mi] = *reinterpret_cast<const s16x8*>(&Plds[w][mi * 16 + c][kk * 32 + q * 8]);
#pragma unroll
    for (int nt = 0; nt < 8; ++nt) {
      s16x8 b = *reinterpret_cast<const s16x8*>(wp + 36864 + (size_t)(kk * 8 + nt) * 512 + l * 8);
#pragma unroll
      for (int mi = 0; mi < 4; ++mi)
        acc2[mi][nt] = MFMA_BF16(a2[mi], b, acc2[mi][nt], 0, 0, 0);
    }
  }
#pragma unroll
  for (int nt = 0; nt < 8; ++nt) {
    float bias = b2[nt * 16 + c];
#pragma unroll
    for (int mi = 0; mi < 4; ++mi)
#pragma unroll
      for (int r = 0; r < 4; ++r) {
        int el = we + mi * 16 + q * 4 + r;
        if ((eb + el) < E) {
          int node = rows_s[el];
          unsafeAtomicAdd(&out[(size_t)node * 128 + nt * 16 + c],
                          acc2[mi][nt][r] + bias);
        }
      }
  }
}

extern "C" void kernel_launch(void* const* d_in, const int* in_sizes, int n_in,
                              void* d_out, int out_size, void* d_ws, size_t ws_size,
                              hipStream_t stream) {
  const float* h    = (const float*)d_in[0];
  const int*   ei   = (const int*)d_in[1];
  const float* bond = (const float*)d_in[2];
  const float* W1   = (const float*)d_in[3];
  const float* b1   = (const float*)d_in[4];
  const float* W2   = (const float*)d_in[5];
  const float* b2   = (const float*)d_in[6];
  float* out = (float*)d_out;
  char* ws = (char*)d_ws;

  const int E  = in_sizes[1] / 2;
  const int NN = in_sizes[0] / 128;

  // ws layout (bytes, 16-aligned)
  short* wp = (short*)ws;                                   // 131072
  size_t off_G    = 131072;
  size_t off_cnt  = off_G + (size_t)NN * 384;               // G: NN*384 B
  size_t off_par  = off_cnt + (((size_t)NN * 4 + 15) & ~15ull);
  size_t off_rce  = off_par + 4096;
  size_t need     = off_rce + (size_t)E * 8;

  hipMemsetAsync(d_out, 0, (size_t)NN * 128 * sizeof(float), stream);
  prep_weights<<<26, 256, 0, stream>>>(W1, W2, wp);

  if (ws_size >= need && NN <= 65535) {
    short* Gs   = (short*)(ws + off_G);
    int*   cnt  = (int*)(ws + off_cnt);
    int*   par  = (int*)(ws + off_par);
    int2*  rce  = (int2*)(ws + off_rce);
    const int NB_G = (NN + 63) / 64;
    const int P    = (NN + 1023) / 1024;

    hipMemsetAsync(cnt, 0, (size_t)NN * 4, stream);
    k_gh<<<NB_G + NB_H, 256, 0, stream>>>(h, wp, Gs, ei, cnt, NN, NB_G, E);
    k_s1<<<P, 1024, 0, stream>>>(cnt, par, NN);
    k_s2<<<1, 1024, 0, stream>>>(par, P);
    k_s3<<<P, 1024, 0, stream>>>(cnt, par, NN);
    k_scatter<<<2048, 256, 0, stream>>>(ei, cnt, rce, E);
    edge_mlp4<<<(E + 127) / 128, 256, 0, stream>>>(Gs, rce, bond, wp, b1, b2, out, E);
  } else {
    edge_mlp<<<(E + 255) / 256, 256, 0, stream>>>(h, ei, bond, wp, b1, b2, out, E);
  }
}